// Round 14
// baseline (276.062 us; speedup 1.0000x reference)
//
#include <hip/hip_runtime.h>
#include <hip/hip_bf16.h>
#include <math.h>

// ---------------- fp16 helpers ----------------

using pkh2 = decltype(__builtin_amdgcn_cvt_pkrtz(0.f, 0.f));   // 2 x __fp16
typedef __fp16 half8v __attribute__((ext_vector_type(8)));     // MFMA A/B frag
typedef __attribute__((ext_vector_type(4))) float f32x4;       // MFMA accumulator

__device__ __forceinline__ unsigned cvt2h(float a, float b) {  // 2xf32 -> packed f16
    pkh2 r = __builtin_amdgcn_cvt_pkrtz(a, b);
    return __builtin_bit_cast(unsigned, r);
}
__device__ __forceinline__ unsigned short f2h(float f) {
    return __builtin_bit_cast(unsigned short, (_Float16)f);
}

// acc += wpair . hpair  (both packed f16 pairs), f32 accumulate
__device__ __forceinline__ float fdot2b(unsigned wp, unsigned hp, float c) {
#if __has_builtin(__builtin_amdgcn_fdot2)
    return __builtin_amdgcn_fdot2(__builtin_bit_cast(pkh2, wp),
                                  __builtin_bit_cast(pkh2, hp), c, false);
#else
    pkh2 w = __builtin_bit_cast(pkh2, wp), h = __builtin_bit_cast(pkh2, hp);
    return fmaf((float)w[0], (float)h[0], fmaf((float)w[1], (float)h[1], c));
#endif
}

// ================= CSR build: bucket-binned counting sort =================

__global__ void init_k(int* __restrict__ bucketCnt) {
    int i = threadIdx.x;
    if (i < 512) bucketCnt[i] = 0;
}

__global__ void bucket_hist_k(const int* __restrict__ ei, int* __restrict__ bucketCnt,
                              int E, int N, int NB) {
    __shared__ int cnt[512];
    for (int t = threadIdx.x; t < 512; t += blockDim.x) cnt[t] = 0;
    __syncthreads();
    const int ITEMS = E + N;
    for (int i = blockIdx.x * blockDim.x + threadIdx.x; i < ITEMS;
         i += gridDim.x * blockDim.x) {
        int d = (i < E) ? ei[E + i] : (i - E);
        atomicAdd(&cnt[d >> 8], 1);
    }
    __syncthreads();
    for (int t = threadIdx.x; t < NB; t += blockDim.x)
        if (cnt[t]) atomicAdd(&bucketCnt[t], cnt[t]);
}

__global__ void bucket_scan_k(const int* __restrict__ bucketCnt,
                              int* __restrict__ bucketOff,
                              int* __restrict__ bucketFill, int NB) {
    __shared__ int ls[512];
    int t = threadIdx.x;
    int v = (t < NB) ? bucketCnt[t] : 0;
    ls[t] = v;
    __syncthreads();
    for (int off = 1; off < 512; off <<= 1) {
        int a = (t >= off) ? ls[t - off] : 0;
        __syncthreads();
        ls[t] += a;
        __syncthreads();
    }
    if (t < NB) { int e = ls[t] - v; bucketOff[t] = e; bucketFill[t] = e; }
}

__global__ __launch_bounds__(256) void bin_scatter_k(const int* __restrict__ ei,
                                                     int* __restrict__ bucketFill,
                                                     int2* __restrict__ binned,
                                                     int E, int N) {
    __shared__ int cnt[512];
    __shared__ int base[512];
    const int ITEMS = E + N;
    const int t = threadIdx.x;
    const int chunk0 = blockIdx.x * 4096;
    for (int b = t; b < 512; b += 256) cnt[b] = 0;
    __syncthreads();
    int s[16], d[16], r[16];
#pragma unroll
    for (int j = 0; j < 16; j++) {
        int i = chunk0 + j * 256 + t;
        if (i < ITEMS) {
            if (i < E) { s[j] = ei[i]; d[j] = ei[E + i]; }
            else       { s[j] = d[j] = i - E; }
            r[j] = atomicAdd(&cnt[d[j] >> 8], 1);
        } else d[j] = -1;
    }
    __syncthreads();
    for (int b = t; b < 512; b += 256) {
        int c = cnt[b];
        base[b] = c ? atomicAdd(&bucketFill[b], c) : 0;
    }
    __syncthreads();
#pragma unroll
    for (int j = 0; j < 16; j++)
        if (d[j] >= 0) binned[base[d[j] >> 8] + r[j]] = make_int2(s[j], d[j]);
}

// fused per-bucket node histogram + LDS scan -> offs written directly
__global__ void node_offs_k(const int2* __restrict__ binned,
                            const int* __restrict__ bucketOff,
                            const int* __restrict__ bucketCnt,
                            int* __restrict__ offs, int N, int ITEMS) {
    __shared__ int cnt[256];
    __shared__ int ls[256];
    const int b = blockIdx.x;
    const int t = threadIdx.x;
    cnt[t] = 0;
    __syncthreads();
    const int beg = bucketOff[b], c = bucketCnt[b];
    for (int i = t; i < c; i += 256)
        atomicAdd(&cnt[binned[beg + i].y & 255], 1);
    __syncthreads();
    int v = cnt[t];
    ls[t] = v;
    __syncthreads();
    for (int off = 1; off < 256; off <<= 1) {
        int a = (t >= off) ? ls[t - off] : 0;
        __syncthreads();
        ls[t] += a;
        __syncthreads();
    }
    int node = b * 256 + t;
    if (node < N) offs[node] = beg + ls[t] - v;
    if (node == N - 1) offs[N] = ITEMS;
}

__global__ void csr_scatter_k(const int2* __restrict__ binned,
                              const int* __restrict__ bucketOff,
                              const int* __restrict__ bucketCnt,
                              const int* __restrict__ offs, int* __restrict__ csr) {
    __shared__ int fill[256];
    const int b = blockIdx.x;
    fill[threadIdx.x] = 0;
    __syncthreads();
    const int beg = bucketOff[b], c = bucketCnt[b];
    for (int i = threadIdx.x; i < c; i += 256) {
        int2 sd = binned[beg + i];
        int r = atomicAdd(&fill[sd.y & 255], 1);
        csr[offs[sd.y] + r] = sd.x;
    }
}

// ======= MFMA GEMM: Y[M,NCOL](f16) = X[M,128] @ W[128,NCOL] + fused alpha =======
// v_mfma_f32_16x16x32_f16, fragment layouts (dtype-independent, m89/m121):
//   A: lane l holds A[l&15][(l>>4)*8 + j];  B: lane l holds B[(l>>4)*8 + j][l&15]
//   D: lane l, reg j -> row (l>>4)*4+j, col l&15

template<int NCOL, bool XF16>
__global__ __launch_bounds__(256) void gemm_alpha_mfma(
        const void* __restrict__ Xv, const float* __restrict__ W,
        const float* __restrict__ asrc, const float* __restrict__ adst,
        unsigned short* __restrict__ Y, float* __restrict__ As,
        float* __restrict__ Ad, int M) {
    constexpr int NT = NCOL / 16;            // 8 (layer1) or 4 (layer2)
    __shared__ alignas(16) short alds[4 * 4 * 64 * 8];      // [w][ks][lane][8]
    __shared__ alignas(16) short blds[NT * 4 * 64 * 8];     // [nt][ks][lane][8]

    const int t    = threadIdx.x;
    const int w    = t >> 6, lane = t & 63;
    const int row0 = blockIdx.x * 64;

    if constexpr (!XF16) {
        const float* X = (const float*)Xv;
#pragma unroll
        for (int i = 0; i < 8; i++) {
            int flat = (i * 256 + t) * 4;
            int r = flat >> 7, k0 = flat & 127;
            int gr = row0 + r;
            float4 v = make_float4(0.f, 0.f, 0.f, 0.f);
            if (gr < M) v = *(const float4*)&X[(size_t)gr * 128 + k0];
            uint2 u = make_uint2(cvt2h(v.x, v.y), cvt2h(v.z, v.w));
            int frag = ((r >> 4) * 4 + (k0 >> 5)) * 64 + ((((k0 & 31) >> 3) << 4) | (r & 15));
            *(uint2*)&alds[frag * 8 + (k0 & 7)] = u;
        }
    } else {
        const unsigned short* X = (const unsigned short*)Xv;
#pragma unroll
        for (int i = 0; i < 4; i++) {
            int flat = (i * 256 + t) * 8;
            int r = flat >> 7, k0 = flat & 127;
            int gr = row0 + r;
            uint4 v = make_uint4(0u, 0u, 0u, 0u);
            if (gr < M) v = *(const uint4*)&X[(size_t)gr * 128 + k0];
            int frag = ((r >> 4) * 4 + (k0 >> 5)) * 64 + ((((k0 & 31) >> 3) << 4) | (r & 15));
            *(uint4*)&alds[frag * 8] = v;   // k0 % 8 == 0
        }
    }

    {
        constexpr int KQ = 256 / NCOL;
        constexpr int BITER = 32 / KQ;
        int c = t % NCOL, kq = t / NCOL;
        int nt = c >> 4, n = c & 15;
#pragma unroll
        for (int i = 0; i < BITER; i++) {
            int k0 = (i * KQ + kq) * 4;
            uint2 u = make_uint2(
                cvt2h(W[(size_t)(k0 + 0) * NCOL + c], W[(size_t)(k0 + 1) * NCOL + c]),
                cvt2h(W[(size_t)(k0 + 2) * NCOL + c], W[(size_t)(k0 + 3) * NCOL + c]));
            int frag = (nt * 4 + (k0 >> 5)) * 64 + ((((k0 & 31) >> 3) << 4) | n);
            *(uint2*)&blds[frag * 8 + (k0 & 7)] = u;
        }
    }
    __syncthreads();

    f32x4 acc[NT];
#pragma unroll
    for (int nt = 0; nt < NT; nt++) acc[nt] = (f32x4){0.f, 0.f, 0.f, 0.f};
#pragma unroll
    for (int ks = 0; ks < 4; ks++) {
        half8v a = *(half8v*)&alds[((w * 4 + ks) * 64 + lane) * 8];
#pragma unroll
        for (int nt = 0; nt < NT; nt++) {
            half8v b = *(half8v*)&blds[((nt * 4 + ks) * 64 + lane) * 8];
            acc[nt] = __builtin_amdgcn_mfma_f32_16x16x32_f16(a, b, acc[nt], 0, 0, 0);
        }
    }

    const int g = lane >> 4, col = lane & 15;
    float ps[4][4] = {}, pd[4][4] = {};
#pragma unroll
    for (int nt = 0; nt < NT; nt++) {
        float av = asrc[nt * 16 + col];
        float dv = adst[nt * 16 + col];
        int h = (NCOL == 128) ? (nt >> 1) : nt;
#pragma unroll
        for (int j = 0; j < 4; j++) {
            float v = acc[nt][j];
            ps[j][h] = fmaf(v, av, ps[j][h]);
            pd[j][h] = fmaf(v, dv, pd[j][h]);
            int gr = row0 + w * 16 + 4 * g + j;
            if (gr < M) Y[(size_t)gr * NCOL + nt * 16 + col] = f2h(v);
        }
    }
#pragma unroll
    for (int m = 1; m < 16; m <<= 1) {
#pragma unroll
        for (int j = 0; j < 4; j++)
#pragma unroll
            for (int h = 0; h < 4; h++) {
                ps[j][h] += __shfl_xor(ps[j][h], m);
                pd[j][h] += __shfl_xor(pd[j][h], m);
            }
    }
    if (col == 0) {
#pragma unroll
        for (int j = 0; j < 4; j++) {
            int gr = row0 + w * 16 + 4 * g + j;
            if (gr < M) {
#pragma unroll
                for (int h = 0; h < 4; h++) {
                    As[gr * 4 + h] = ps[j][h];
                    Ad[gr * 4 + h] = pd[j][h];
                }
            }
        }
    }
}

// ------- aggregation: one wave per dst node ----------------------------------
// out[i] = ( sum_{e:dst=i} exp(leaky(As[src]+Ad[i])) * h[src] ) / sum exp(...)
// (segment-max dropped: softmax ratio invariant; weights < e^~5 -> f16-safe)
// Four edges per lane in flight + f16 perm/fdot2 accumulate. Register-only.

template<bool RELU>
__global__ void agg128_k(const unsigned short* __restrict__ Hb,
                         const float* __restrict__ As, const float* __restrict__ Ad,
                         const int* __restrict__ offs, const int* __restrict__ csr,
                         const float* __restrict__ bias,
                         unsigned short* __restrict__ Outb, int n) {
    int wid  = (blockIdx.x * blockDim.x + threadIdx.x) >> 6;
    int lane = threadIdx.x & 63;
    if (wid >= n) return;
    const int g = lane >> 4;          // edge-slot group (0..3)
    const int q = lane & 15;          // channel octet
    const int head = q >> 2;
    const int beg = offs[wid], end = offs[wid + 1];
    const float ad = Ad[wid * 4 + head];
    float acc[8];
#pragma unroll
    for (int k = 0; k < 8; k++) acc[k] = 0.f;
    float sw = 0.f;

    for (int cb = beg; cb < end; cb += 64) {
        const int nc = min(64, end - cb);
        const int sreg = csr[cb + (lane < nc ? lane : 0)];   // 1 coalesced load
        const int ncr = (nc + 15) & ~15;
        for (int j = 0; j < ncr; j += 16) {
            const int e0 = j + g, e1 = e0 + 4, e2 = e0 + 8, e3 = e0 + 12;
            const bool v0 = e0 < nc, v1 = e1 < nc, v2 = e2 < nc, v3 = e3 < nc;
            const int s0 = __shfl(sreg, v0 ? e0 : 0);
            const int s1 = __shfl(sreg, v1 ? e1 : 0);
            const int s2 = __shfl(sreg, v2 ? e2 : 0);
            const int s3 = __shfl(sreg, v3 ? e3 : 0);
            const uint4 hA = *(const uint4*)&Hb[(size_t)s0 * 128 + q * 8];
            const uint4 hB = *(const uint4*)&Hb[(size_t)s1 * 128 + q * 8];
            const uint4 hC = *(const uint4*)&Hb[(size_t)s2 * 128 + q * 8];
            const uint4 hD = *(const uint4*)&Hb[(size_t)s3 * 128 + q * 8];
            float ev0 = As[s0 * 4 + head] + ad; ev0 = ev0 > 0.f ? ev0 : 0.2f * ev0;
            float ev1 = As[s1 * 4 + head] + ad; ev1 = ev1 > 0.f ? ev1 : 0.2f * ev1;
            float ev2 = As[s2 * 4 + head] + ad; ev2 = ev2 > 0.f ? ev2 : 0.2f * ev2;
            float ev3 = As[s3 * 4 + head] + ad; ev3 = ev3 > 0.f ? ev3 : 0.2f * ev3;
            const float w0 = v0 ? __expf(ev0) : 0.f;
            const float w1 = v1 ? __expf(ev1) : 0.f;
            const float w2 = v2 ? __expf(ev2) : 0.f;
            const float w3 = v3 ? __expf(ev3) : 0.f;
            sw += (w0 + w1) + (w2 + w3);
            const unsigned wp01 = cvt2h(w0, w1);
            const unsigned wp23 = cvt2h(w2, w3);
#pragma unroll
            for (int k = 0; k < 4; k++) {
                unsigned a0 = (&hA.x)[k], a1 = (&hB.x)[k];
                unsigned a2 = (&hC.x)[k], a3 = (&hD.x)[k];
                acc[2 * k]     = fdot2b(wp01, __builtin_amdgcn_perm(a1, a0, 0x05040100u), acc[2 * k]);
                acc[2 * k]     = fdot2b(wp23, __builtin_amdgcn_perm(a3, a2, 0x05040100u), acc[2 * k]);
                acc[2 * k + 1] = fdot2b(wp01, __builtin_amdgcn_perm(a1, a0, 0x07060302u), acc[2 * k + 1]);
                acc[2 * k + 1] = fdot2b(wp23, __builtin_amdgcn_perm(a3, a2, 0x07060302u), acc[2 * k + 1]);
            }
        }
    }

    sw += __shfl_xor(sw, 16); sw += __shfl_xor(sw, 32);
#pragma unroll
    for (int k = 0; k < 8; k++) {
        acc[k] += __shfl_xor(acc[k], 16);
        acc[k] += __shfl_xor(acc[k], 32);
    }
    if (g == 0) {
        const float inv = 1.f / sw;
        float o[8];
#pragma unroll
        for (int k = 0; k < 8; k++) {
            float v = fmaf(acc[k], inv, bias[q * 8 + k]);
            if (RELU) v = fmaxf(v, 0.f);
            o[k] = v;
        }
        uint4 ov = make_uint4(cvt2h(o[0], o[1]), cvt2h(o[2], o[3]),
                              cvt2h(o[4], o[5]), cvt2h(o[6], o[7]));
        *(uint4*)&Outb[(size_t)wid * 128 + q * 8] = ov;
    }
}

// Layer-2 aggregate FUSED with global add pool, grid-strided over nodes.
// Per-wave register accumulation across its nodes; block LDS-reduces and
// writes 64 PARTIAL sums to part[bid*64+c] with plain stores -- NO global
// atomics (R12/R13 lesson: same-line atomic RMW throughput ~1.5ns, 1024+
// blocks of 64-ch atomics = 20-600us of serialized tail). reduce_fc_k sums
// the partials. bias*N folded there.

__global__ __launch_bounds__(256) void agg64_pool_k(
        const unsigned short* __restrict__ Hb,
        const float* __restrict__ As, const float* __restrict__ Ad,
        const int* __restrict__ offs, const int* __restrict__ csr,
        float* __restrict__ part, int n) {
    __shared__ float gl[64];
    const int t = threadIdx.x;
    if (t < 64) gl[t] = 0.f;
    __syncthreads();
    const int wave0  = (blockIdx.x * blockDim.x + t) >> 6;
    const int nWaves = (gridDim.x * blockDim.x) >> 6;
    const int lane = t & 63;
    const int g = lane >> 3;          // edge-slot group (0..7)
    const int q = lane & 7;           // channel octet
    const int head = q >> 1;
    float gsum[8];
#pragma unroll
    for (int k = 0; k < 8; k++) gsum[k] = 0.f;

    for (int wid = wave0; wid < n; wid += nWaves) {
        const int beg = offs[wid], end = offs[wid + 1];
        const float ad = Ad[wid * 4 + head];
        float acc[8];
#pragma unroll
        for (int k = 0; k < 8; k++) acc[k] = 0.f;
        float sw = 0.f;
        for (int cb = beg; cb < end; cb += 64) {
            const int nc = min(64, end - cb);
            const int sreg = csr[cb + (lane < nc ? lane : 0)];
            const int ncr = (nc + 31) & ~31;
            for (int j = 0; j < ncr; j += 32) {
                const int e0 = j + g, e1 = e0 + 8, e2 = e0 + 16, e3 = e0 + 24;
                const bool v0 = e0 < nc, v1 = e1 < nc, v2 = e2 < nc, v3 = e3 < nc;
                const int s0 = __shfl(sreg, v0 ? e0 : 0);
                const int s1 = __shfl(sreg, v1 ? e1 : 0);
                const int s2 = __shfl(sreg, v2 ? e2 : 0);
                const int s3 = __shfl(sreg, v3 ? e3 : 0);
                const uint4 hA = *(const uint4*)&Hb[(size_t)s0 * 64 + q * 8];
                const uint4 hB = *(const uint4*)&Hb[(size_t)s1 * 64 + q * 8];
                const uint4 hC = *(const uint4*)&Hb[(size_t)s2 * 64 + q * 8];
                const uint4 hD = *(const uint4*)&Hb[(size_t)s3 * 64 + q * 8];
                float ev0 = As[s0 * 4 + head] + ad; ev0 = ev0 > 0.f ? ev0 : 0.2f * ev0;
                float ev1 = As[s1 * 4 + head] + ad; ev1 = ev1 > 0.f ? ev1 : 0.2f * ev1;
                float ev2 = As[s2 * 4 + head] + ad; ev2 = ev2 > 0.f ? ev2 : 0.2f * ev2;
                float ev3 = As[s3 * 4 + head] + ad; ev3 = ev3 > 0.f ? ev3 : 0.2f * ev3;
                const float w0 = v0 ? __expf(ev0) : 0.f;
                const float w1 = v1 ? __expf(ev1) : 0.f;
                const float w2 = v2 ? __expf(ev2) : 0.f;
                const float w3 = v3 ? __expf(ev3) : 0.f;
                sw += (w0 + w1) + (w2 + w3);
                const unsigned wp01 = cvt2h(w0, w1);
                const unsigned wp23 = cvt2h(w2, w3);
#pragma unroll
                for (int k = 0; k < 4; k++) {
                    unsigned a0 = (&hA.x)[k], a1 = (&hB.x)[k];
                    unsigned a2 = (&hC.x)[k], a3 = (&hD.x)[k];
                    acc[2 * k]     = fdot2b(wp01, __builtin_amdgcn_perm(a1, a0, 0x05040100u), acc[2 * k]);
                    acc[2 * k]     = fdot2b(wp23, __builtin_amdgcn_perm(a3, a2, 0x05040100u), acc[2 * k]);
                    acc[2 * k + 1] = fdot2b(wp01, __builtin_amdgcn_perm(a1, a0, 0x07060302u), acc[2 * k + 1]);
                    acc[2 * k + 1] = fdot2b(wp23, __builtin_amdgcn_perm(a3, a2, 0x07060302u), acc[2 * k + 1]);
                }
            }
        }
        sw += __shfl_xor(sw, 8); sw += __shfl_xor(sw, 16); sw += __shfl_xor(sw, 32);
#pragma unroll
        for (int k = 0; k < 8; k++) {
            acc[k] += __shfl_xor(acc[k], 8);
            acc[k] += __shfl_xor(acc[k], 16);
            acc[k] += __shfl_xor(acc[k], 32);
        }
        if (g == 0) {
            const float inv = 1.f / sw;
#pragma unroll
            for (int k = 0; k < 8; k++) gsum[k] = fmaf(acc[k], inv, gsum[k]);
        }
    }

    if (g == 0) {
#pragma unroll
        for (int k = 0; k < 8; k++) atomicAdd(&gl[q * 8 + k], gsum[k]);  // LDS only
    }
    __syncthreads();
    if (t < 64) part[(size_t)blockIdx.x * 64 + t] = gl[t];   // plain store
}

// ---- reduce partials (nPart x 64) + fold N*b2 + FC, single block ----

__global__ __launch_bounds__(1024) void reduce_fc_k(
        const float* __restrict__ part, const float* __restrict__ b2,
        const float* __restrict__ w, const float* __restrict__ b,
        float* __restrict__ out, int n, int nPart) {
    __shared__ float ls[1024];
    const int t = threadIdx.x;
    const int c = t & 63, pg = t >> 6;          // 16 p-groups x 64 channels
    float acc = 0.f;
    for (int p = pg; p < nPart; p += 16) acc += part[(size_t)p * 64 + c];
    ls[t] = acc;
    __syncthreads();
    if (t < 64) {
        float s = 0.f;
#pragma unroll
        for (int i = 0; i < 16; i++) s += ls[i * 64 + t];   // reads column t only
        ls[t] = s + (float)n * b2[t];                        // fold layer-2 bias
    }
    __syncthreads();
    if (t < 2) {
        float a = b[t];
        for (int cc = 0; cc < 64; cc++) a = fmaf(ls[cc], w[cc * 2 + t], a);
        out[t] = a;
    }
}

// ---------------- launch ----------------

static inline size_t align256(size_t x) { return (x + 255) & ~(size_t)255; }

extern "C" void kernel_launch(void* const* d_in, const int* in_sizes, int n_in,
                              void* d_out, int out_size, void* d_ws, size_t ws_size,
                              hipStream_t stream) {
    const float* x     = (const float*)d_in[0];
    const int*   ei    = (const int*)  d_in[1];
    const float* W1    = (const float*)d_in[2];
    const float* asrc1 = (const float*)d_in[3];
    const float* adst1 = (const float*)d_in[4];
    const float* b1    = (const float*)d_in[5];
    const float* W2    = (const float*)d_in[6];
    const float* asrc2 = (const float*)d_in[7];
    const float* adst2 = (const float*)d_in[8];
    const float* b2    = (const float*)d_in[9];
    const float* fcw   = (const float*)d_in[10];
    const float* fcb   = (const float*)d_in[11];
    float* out = (float*)d_out;

    const int N = in_sizes[0] / 128;
    const int E = in_sizes[1] / 2;
    const int ITEMS = E + N;
    const int NB = (N + 255) >> 8;
    const int NPOOL = 2048;           // agg64_pool grid: 8 blocks/CU -> 100% occ bound

    // workspace carve-up
    char* w = (char*)d_ws;
    size_t off = 0;
    int* offs  = (int*)(w + off); off = align256(off + (size_t)(N + 1) * 4);
    int* bCnt  = (int*)(w + off); off = align256(off + 512 * 4);
    int* bOff  = (int*)(w + off); off = align256(off + 512 * 4);
    int* bFill = (int*)(w + off); off = align256(off + 512 * 4);
    int* csr   = (int*)(w + off); off = align256(off + (size_t)ITEMS * 4);
    int2* binned = (int2*)(w + off); off = align256(off + (size_t)ITEMS * 8);
    float* As = (float*)(w + off); off = align256(off + (size_t)N * 4 * 4);
    float* Ad = (float*)(w + off); off = align256(off + (size_t)N * 4 * 4);
    float* part = (float*)(w + off); off = align256(off + (size_t)NPOOL * 64 * 4);
    unsigned short* bufH = (unsigned short*)(w + off); off = align256(off + (size_t)N * 128 * 2);
    unsigned short* bufO = (unsigned short*)(w + off); off = align256(off + (size_t)N * 128 * 2);

    // --- build CSR (by dst, self loops included) ---
    init_k<<<1, 512, 0, stream>>>(bCnt);
    bucket_hist_k<<<1024, 256, 0, stream>>>(ei, bCnt, E, N, NB);
    bucket_scan_k<<<1, 512, 0, stream>>>(bCnt, bOff, bFill, NB);
    bin_scatter_k<<<(ITEMS + 4095) / 4096, 256, 0, stream>>>(ei, bFill, binned, E, N);
    node_offs_k<<<NB, 256, 0, stream>>>(binned, bOff, bCnt, offs, N, ITEMS);
    csr_scatter_k<<<NB, 256, 0, stream>>>(binned, bOff, bCnt, offs, csr);

    // --- layer 1 ---
    gemm_alpha_mfma<128, false><<<(N + 63) / 64, 256, 0, stream>>>(
        x, W1, asrc1, adst1, bufH, As, Ad, N);
    agg128_k<true><<<(N * 64 + 255) / 256, 256, 0, stream>>>(
        bufH, As, Ad, offs, csr, b1, bufO, N);

    // --- layer 2 ---
    gemm_alpha_mfma<64, true><<<(N + 63) / 64, 256, 0, stream>>>(
        bufO, W2, asrc2, adst2, bufH, As, Ad, N);
    agg64_pool_k<<<NPOOL, 256, 0, stream>>>(
        bufH, As, Ad, offs, csr, part, N);

    // --- reduce partials + fc ---
    reduce_fc_k<<<1, 1024, 0, stream>>>(part, b2, fcw, fcb, out, N, NPOOL);
}

// Round 15
// 248.348 us; speedup vs baseline: 1.1116x; 1.1116x over previous
//
#include <hip/hip_runtime.h>
#include <hip/hip_bf16.h>
#include <math.h>

// ---------------- fp16 helpers ----------------

using pkh2 = decltype(__builtin_amdgcn_cvt_pkrtz(0.f, 0.f));   // 2 x __fp16
typedef __fp16 half8v __attribute__((ext_vector_type(8)));     // MFMA A/B frag
typedef __attribute__((ext_vector_type(4))) float f32x4;       // MFMA accumulator

__device__ __forceinline__ unsigned cvt2h(float a, float b) {  // 2xf32 -> packed f16
    pkh2 r = __builtin_amdgcn_cvt_pkrtz(a, b);
    return __builtin_bit_cast(unsigned, r);
}
__device__ __forceinline__ unsigned short f2h(float f) {
    return __builtin_bit_cast(unsigned short, (_Float16)f);
}

// acc += wpair . hpair  (both packed f16 pairs), f32 accumulate
__device__ __forceinline__ float fdot2b(unsigned wp, unsigned hp, float c) {
#if __has_builtin(__builtin_amdgcn_fdot2)
    return __builtin_amdgcn_fdot2(__builtin_bit_cast(pkh2, wp),
                                  __builtin_bit_cast(pkh2, hp), c, false);
#else
    pkh2 w = __builtin_bit_cast(pkh2, wp), h = __builtin_bit_cast(pkh2, hp);
    return fmaf((float)w[0], (float)h[0], fmaf((float)w[1], (float)h[1], c));
#endif
}

// ================= CSR build v3: fixed-capacity buckets =================
// Random dst -> bucket counts Poisson(mu~4350, sigma~66); CAP=8192 is ~58 sigma
// headroom, so NO histogram pre-pass is needed. Chain: memsetAsync(fill) ->
// bin_scatter (LDS rank + global chunk reserve, bucket slot b*CAP) ->
// bucket_scan (counts -> csr base offsets) -> csr_build (fused per-bucket
// hist + scan + offs write + scatter; 2nd binned pass is L2-hot).

#define BCAP_LOG 13                      // 8192 items per bucket

__global__ __launch_bounds__(256) void bin_scatter_k(const int* __restrict__ ei,
                                                     int* __restrict__ bucketFill,
                                                     int2* __restrict__ binned,
                                                     int E, int N) {
    __shared__ int cnt[512];
    __shared__ int base[512];
    const int ITEMS = E + N;
    const int t = threadIdx.x;
    const int chunk0 = blockIdx.x * 4096;
    for (int b = t; b < 512; b += 256) cnt[b] = 0;
    __syncthreads();
    int s[16], d[16], r[16];
#pragma unroll
    for (int j = 0; j < 16; j++) {
        int i = chunk0 + j * 256 + t;
        if (i < ITEMS) {
            if (i < E) { s[j] = ei[i]; d[j] = ei[E + i]; }
            else       { s[j] = d[j] = i - E; }
            r[j] = atomicAdd(&cnt[d[j] >> 8], 1);
        } else d[j] = -1;
    }
    __syncthreads();
    for (int b = t; b < 512; b += 256) {
        int c = cnt[b];
        base[b] = c ? atomicAdd(&bucketFill[b], c) : 0;   // global chunk reserve
    }
    __syncthreads();
#pragma unroll
    for (int j = 0; j < 16; j++)
        if (d[j] >= 0) {
            int b = d[j] >> 8;
            binned[((size_t)b << BCAP_LOG) + base[b] + r[j]] = make_int2(s[j], d[j]);
        }
}

// exclusive prefix over bucket counts -> csr base offset per bucket
__global__ void bucket_scan_k(const int* __restrict__ bucketCnt,
                              int* __restrict__ bucketOff, int NB) {
    __shared__ int ls[512];
    int t = threadIdx.x;
    int v = (t < NB) ? bucketCnt[t] : 0;
    ls[t] = v;
    __syncthreads();
    for (int off = 1; off < 512; off <<= 1) {
        int a = (t >= off) ? ls[t - off] : 0;
        __syncthreads();
        ls[t] += a;
        __syncthreads();
    }
    if (t < NB) bucketOff[t] = ls[t] - v;
}

// fused per-bucket: node histogram + scan + offs write + csr scatter
__global__ void csr_build_k(const int2* __restrict__ binned,
                            const int* __restrict__ bucketOff,
                            const int* __restrict__ bucketCnt,
                            int* __restrict__ offs, int* __restrict__ csr,
                            int N, int ITEMS) {
    __shared__ int cnt[256];
    __shared__ int obase[256];
    __shared__ int fill[256];
    const int b = blockIdx.x, t = threadIdx.x;
    cnt[t] = 0; fill[t] = 0;
    __syncthreads();
    const int c = bucketCnt[b];
    const int2* bp = &binned[(size_t)b << BCAP_LOG];
    for (int i = t; i < c; i += 256)
        atomicAdd(&cnt[bp[i].y & 255], 1);
    __syncthreads();
    int v = cnt[t];
    obase[t] = v;
    __syncthreads();
    for (int off = 1; off < 256; off <<= 1) {
        int a = (t >= off) ? obase[t - off] : 0;
        __syncthreads();
        obase[t] += a;
        __syncthreads();
    }
    obase[t] -= v;                        // bucket-local exclusive scan
    const int beg = bucketOff[b];
    int node = b * 256 + t;
    if (node < N) offs[node] = beg + obase[t];
    if (node == N - 1) offs[N] = ITEMS;
    __syncthreads();
    for (int i = t; i < c; i += 256) {    // 2nd pass: L2-hot (same block/XCD)
        int2 sd = bp[i];
        int r = atomicAdd(&fill[sd.y & 255], 1);
        csr[beg + obase[sd.y & 255] + r] = sd.x;
    }
}

// ======= MFMA GEMM: Y[M,NCOL](f16) = X[M,128] @ W[128,NCOL] + fused alpha =======
// v_mfma_f32_16x16x32_f16, fragment layouts (dtype-independent, m89/m121):
//   A: lane l holds A[l&15][(l>>4)*8 + j];  B: lane l holds B[(l>>4)*8 + j][l&15]
//   D: lane l, reg j -> row (l>>4)*4+j, col l&15

template<int NCOL, bool XF16>
__global__ __launch_bounds__(256) void gemm_alpha_mfma(
        const void* __restrict__ Xv, const float* __restrict__ W,
        const float* __restrict__ asrc, const float* __restrict__ adst,
        unsigned short* __restrict__ Y, float* __restrict__ As,
        float* __restrict__ Ad, int M) {
    constexpr int NT = NCOL / 16;            // 8 (layer1) or 4 (layer2)
    __shared__ alignas(16) short alds[4 * 4 * 64 * 8];      // [w][ks][lane][8]
    __shared__ alignas(16) short blds[NT * 4 * 64 * 8];     // [nt][ks][lane][8]

    const int t    = threadIdx.x;
    const int w    = t >> 6, lane = t & 63;
    const int row0 = blockIdx.x * 64;

    if constexpr (!XF16) {
        const float* X = (const float*)Xv;
#pragma unroll
        for (int i = 0; i < 8; i++) {
            int flat = (i * 256 + t) * 4;
            int r = flat >> 7, k0 = flat & 127;
            int gr = row0 + r;
            float4 v = make_float4(0.f, 0.f, 0.f, 0.f);
            if (gr < M) v = *(const float4*)&X[(size_t)gr * 128 + k0];
            uint2 u = make_uint2(cvt2h(v.x, v.y), cvt2h(v.z, v.w));
            int frag = ((r >> 4) * 4 + (k0 >> 5)) * 64 + ((((k0 & 31) >> 3) << 4) | (r & 15));
            *(uint2*)&alds[frag * 8 + (k0 & 7)] = u;
        }
    } else {
        const unsigned short* X = (const unsigned short*)Xv;
#pragma unroll
        for (int i = 0; i < 4; i++) {
            int flat = (i * 256 + t) * 8;
            int r = flat >> 7, k0 = flat & 127;
            int gr = row0 + r;
            uint4 v = make_uint4(0u, 0u, 0u, 0u);
            if (gr < M) v = *(const uint4*)&X[(size_t)gr * 128 + k0];
            int frag = ((r >> 4) * 4 + (k0 >> 5)) * 64 + ((((k0 & 31) >> 3) << 4) | (r & 15));
            *(uint4*)&alds[frag * 8] = v;   // k0 % 8 == 0
        }
    }

    {
        constexpr int KQ = 256 / NCOL;
        constexpr int BITER = 32 / KQ;
        int c = t % NCOL, kq = t / NCOL;
        int nt = c >> 4, n = c & 15;
#pragma unroll
        for (int i = 0; i < BITER; i++) {
            int k0 = (i * KQ + kq) * 4;
            uint2 u = make_uint2(
                cvt2h(W[(size_t)(k0 + 0) * NCOL + c], W[(size_t)(k0 + 1) * NCOL + c]),
                cvt2h(W[(size_t)(k0 + 2) * NCOL + c], W[(size_t)(k0 + 3) * NCOL + c]));
            int frag = (nt * 4 + (k0 >> 5)) * 64 + ((((k0 & 31) >> 3) << 4) | n);
            *(uint2*)&blds[frag * 8 + (k0 & 7)] = u;
        }
    }
    __syncthreads();

    f32x4 acc[NT];
#pragma unroll
    for (int nt = 0; nt < NT; nt++) acc[nt] = (f32x4){0.f, 0.f, 0.f, 0.f};
#pragma unroll
    for (int ks = 0; ks < 4; ks++) {
        half8v a = *(half8v*)&alds[((w * 4 + ks) * 64 + lane) * 8];
#pragma unroll
        for (int nt = 0; nt < NT; nt++) {
            half8v b = *(half8v*)&blds[((nt * 4 + ks) * 64 + lane) * 8];
            acc[nt] = __builtin_amdgcn_mfma_f32_16x16x32_f16(a, b, acc[nt], 0, 0, 0);
        }
    }

    const int g = lane >> 4, col = lane & 15;
    float ps[4][4] = {}, pd[4][4] = {};
#pragma unroll
    for (int nt = 0; nt < NT; nt++) {
        float av = asrc[nt * 16 + col];
        float dv = adst[nt * 16 + col];
        int h = (NCOL == 128) ? (nt >> 1) : nt;
#pragma unroll
        for (int j = 0; j < 4; j++) {
            float v = acc[nt][j];
            ps[j][h] = fmaf(v, av, ps[j][h]);
            pd[j][h] = fmaf(v, dv, pd[j][h]);
            int gr = row0 + w * 16 + 4 * g + j;
            if (gr < M) Y[(size_t)gr * NCOL + nt * 16 + col] = f2h(v);
        }
    }
#pragma unroll
    for (int m = 1; m < 16; m <<= 1) {
#pragma unroll
        for (int j = 0; j < 4; j++)
#pragma unroll
            for (int h = 0; h < 4; h++) {
                ps[j][h] += __shfl_xor(ps[j][h], m);
                pd[j][h] += __shfl_xor(pd[j][h], m);
            }
    }
    if (col == 0) {
#pragma unroll
        for (int j = 0; j < 4; j++) {
            int gr = row0 + w * 16 + 4 * g + j;
            if (gr < M) {
#pragma unroll
                for (int h = 0; h < 4; h++) {
                    As[gr * 4 + h] = ps[j][h];
                    Ad[gr * 4 + h] = pd[j][h];
                }
            }
        }
    }
}

// ------- aggregation: one wave per dst node ----------------------------------
// out[i] = ( sum_{e:dst=i} exp(leaky(As[src]+Ad[i])) * h[src] ) / sum exp(...)
// (segment-max dropped: softmax ratio invariant; weights < e^~5 -> f16-safe)
// Four edges per lane in flight + f16 perm/fdot2 accumulate. Register-only.
// R7/R11/R14 all land at 72us: random-gather floor (logical ~6.5 TB/s).

template<bool RELU>
__global__ void agg128_k(const unsigned short* __restrict__ Hb,
                         const float* __restrict__ As, const float* __restrict__ Ad,
                         const int* __restrict__ offs, const int* __restrict__ csr,
                         const float* __restrict__ bias,
                         unsigned short* __restrict__ Outb, int n) {
    int wid  = (blockIdx.x * blockDim.x + threadIdx.x) >> 6;
    int lane = threadIdx.x & 63;
    if (wid >= n) return;
    const int g = lane >> 4;          // edge-slot group (0..3)
    const int q = lane & 15;          // channel octet
    const int head = q >> 2;
    const int beg = offs[wid], end = offs[wid + 1];
    const float ad = Ad[wid * 4 + head];
    float acc[8];
#pragma unroll
    for (int k = 0; k < 8; k++) acc[k] = 0.f;
    float sw = 0.f;

    for (int cb = beg; cb < end; cb += 64) {
        const int nc = min(64, end - cb);
        const int sreg = csr[cb + (lane < nc ? lane : 0)];   // 1 coalesced load
        const int ncr = (nc + 15) & ~15;
        for (int j = 0; j < ncr; j += 16) {
            const int e0 = j + g, e1 = e0 + 4, e2 = e0 + 8, e3 = e0 + 12;
            const bool v0 = e0 < nc, v1 = e1 < nc, v2 = e2 < nc, v3 = e3 < nc;
            const int s0 = __shfl(sreg, v0 ? e0 : 0);
            const int s1 = __shfl(sreg, v1 ? e1 : 0);
            const int s2 = __shfl(sreg, v2 ? e2 : 0);
            const int s3 = __shfl(sreg, v3 ? e3 : 0);
            const uint4 hA = *(const uint4*)&Hb[(size_t)s0 * 128 + q * 8];
            const uint4 hB = *(const uint4*)&Hb[(size_t)s1 * 128 + q * 8];
            const uint4 hC = *(const uint4*)&Hb[(size_t)s2 * 128 + q * 8];
            const uint4 hD = *(const uint4*)&Hb[(size_t)s3 * 128 + q * 8];
            float ev0 = As[s0 * 4 + head] + ad; ev0 = ev0 > 0.f ? ev0 : 0.2f * ev0;
            float ev1 = As[s1 * 4 + head] + ad; ev1 = ev1 > 0.f ? ev1 : 0.2f * ev1;
            float ev2 = As[s2 * 4 + head] + ad; ev2 = ev2 > 0.f ? ev2 : 0.2f * ev2;
            float ev3 = As[s3 * 4 + head] + ad; ev3 = ev3 > 0.f ? ev3 : 0.2f * ev3;
            const float w0 = v0 ? __expf(ev0) : 0.f;
            const float w1 = v1 ? __expf(ev1) : 0.f;
            const float w2 = v2 ? __expf(ev2) : 0.f;
            const float w3 = v3 ? __expf(ev3) : 0.f;
            sw += (w0 + w1) + (w2 + w3);
            const unsigned wp01 = cvt2h(w0, w1);
            const unsigned wp23 = cvt2h(w2, w3);
#pragma unroll
            for (int k = 0; k < 4; k++) {
                unsigned a0 = (&hA.x)[k], a1 = (&hB.x)[k];
                unsigned a2 = (&hC.x)[k], a3 = (&hD.x)[k];
                acc[2 * k]     = fdot2b(wp01, __builtin_amdgcn_perm(a1, a0, 0x05040100u), acc[2 * k]);
                acc[2 * k]     = fdot2b(wp23, __builtin_amdgcn_perm(a3, a2, 0x05040100u), acc[2 * k]);
                acc[2 * k + 1] = fdot2b(wp01, __builtin_amdgcn_perm(a1, a0, 0x07060302u), acc[2 * k + 1]);
                acc[2 * k + 1] = fdot2b(wp23, __builtin_amdgcn_perm(a3, a2, 0x07060302u), acc[2 * k + 1]);
            }
        }
    }

    sw += __shfl_xor(sw, 16); sw += __shfl_xor(sw, 32);
#pragma unroll
    for (int k = 0; k < 8; k++) {
        acc[k] += __shfl_xor(acc[k], 16);
        acc[k] += __shfl_xor(acc[k], 32);
    }
    if (g == 0) {
        const float inv = 1.f / sw;
        float o[8];
#pragma unroll
        for (int k = 0; k < 8; k++) {
            float v = fmaf(acc[k], inv, bias[q * 8 + k]);
            if (RELU) v = fmaxf(v, 0.f);
            o[k] = v;
        }
        uint4 ov = make_uint4(cvt2h(o[0], o[1]), cvt2h(o[2], o[3]),
                              cvt2h(o[4], o[5]), cvt2h(o[6], o[7]));
        *(uint4*)&Outb[(size_t)wid * 128 + q * 8] = ov;
    }
}

// Layer-2 aggregate FUSED with global add pool, grid-strided over nodes.
// Per-wave register accumulation; per-block partial stores (NO global atomics).

__global__ __launch_bounds__(256) void agg64_pool_k(
        const unsigned short* __restrict__ Hb,
        const float* __restrict__ As, const float* __restrict__ Ad,
        const int* __restrict__ offs, const int* __restrict__ csr,
        float* __restrict__ part, int n) {
    __shared__ float gl[64];
    const int t = threadIdx.x;
    if (t < 64) gl[t] = 0.f;
    __syncthreads();
    const int wave0  = (blockIdx.x * blockDim.x + t) >> 6;
    const int nWaves = (gridDim.x * blockDim.x) >> 6;
    const int lane = t & 63;
    const int g = lane >> 3;          // edge-slot group (0..7)
    const int q = lane & 7;           // channel octet
    const int head = q >> 1;
    float gsum[8];
#pragma unroll
    for (int k = 0; k < 8; k++) gsum[k] = 0.f;

    for (int wid = wave0; wid < n; wid += nWaves) {
        const int beg = offs[wid], end = offs[wid + 1];
        const float ad = Ad[wid * 4 + head];
        float acc[8];
#pragma unroll
        for (int k = 0; k < 8; k++) acc[k] = 0.f;
        float sw = 0.f;
        for (int cb = beg; cb < end; cb += 64) {
            const int nc = min(64, end - cb);
            const int sreg = csr[cb + (lane < nc ? lane : 0)];
            const int ncr = (nc + 31) & ~31;
            for (int j = 0; j < ncr; j += 32) {
                const int e0 = j + g, e1 = e0 + 8, e2 = e0 + 16, e3 = e0 + 24;
                const bool v0 = e0 < nc, v1 = e1 < nc, v2 = e2 < nc, v3 = e3 < nc;
                const int s0 = __shfl(sreg, v0 ? e0 : 0);
                const int s1 = __shfl(sreg, v1 ? e1 : 0);
                const int s2 = __shfl(sreg, v2 ? e2 : 0);
                const int s3 = __shfl(sreg, v3 ? e3 : 0);
                const uint4 hA = *(const uint4*)&Hb[(size_t)s0 * 64 + q * 8];
                const uint4 hB = *(const uint4*)&Hb[(size_t)s1 * 64 + q * 8];
                const uint4 hC = *(const uint4*)&Hb[(size_t)s2 * 64 + q * 8];
                const uint4 hD = *(const uint4*)&Hb[(size_t)s3 * 64 + q * 8];
                float ev0 = As[s0 * 4 + head] + ad; ev0 = ev0 > 0.f ? ev0 : 0.2f * ev0;
                float ev1 = As[s1 * 4 + head] + ad; ev1 = ev1 > 0.f ? ev1 : 0.2f * ev1;
                float ev2 = As[s2 * 4 + head] + ad; ev2 = ev2 > 0.f ? ev2 : 0.2f * ev2;
                float ev3 = As[s3 * 4 + head] + ad; ev3 = ev3 > 0.f ? ev3 : 0.2f * ev3;
                const float w0 = v0 ? __expf(ev0) : 0.f;
                const float w1 = v1 ? __expf(ev1) : 0.f;
                const float w2 = v2 ? __expf(ev2) : 0.f;
                const float w3 = v3 ? __expf(ev3) : 0.f;
                sw += (w0 + w1) + (w2 + w3);
                const unsigned wp01 = cvt2h(w0, w1);
                const unsigned wp23 = cvt2h(w2, w3);
#pragma unroll
                for (int k = 0; k < 4; k++) {
                    unsigned a0 = (&hA.x)[k], a1 = (&hB.x)[k];
                    unsigned a2 = (&hC.x)[k], a3 = (&hD.x)[k];
                    acc[2 * k]     = fdot2b(wp01, __builtin_amdgcn_perm(a1, a0, 0x05040100u), acc[2 * k]);
                    acc[2 * k]     = fdot2b(wp23, __builtin_amdgcn_perm(a3, a2, 0x05040100u), acc[2 * k]);
                    acc[2 * k + 1] = fdot2b(wp01, __builtin_amdgcn_perm(a1, a0, 0x07060302u), acc[2 * k + 1]);
                    acc[2 * k + 1] = fdot2b(wp23, __builtin_amdgcn_perm(a3, a2, 0x07060302u), acc[2 * k + 1]);
                }
            }
        }
        sw += __shfl_xor(sw, 8); sw += __shfl_xor(sw, 16); sw += __shfl_xor(sw, 32);
#pragma unroll
        for (int k = 0; k < 8; k++) {
            acc[k] += __shfl_xor(acc[k], 8);
            acc[k] += __shfl_xor(acc[k], 16);
            acc[k] += __shfl_xor(acc[k], 32);
        }
        if (g == 0) {
            const float inv = 1.f / sw;
#pragma unroll
            for (int k = 0; k < 8; k++) gsum[k] = fmaf(acc[k], inv, gsum[k]);
        }
    }

    if (g == 0) {
#pragma unroll
        for (int k = 0; k < 8; k++) atomicAdd(&gl[q * 8 + k], gsum[k]);  // LDS only
    }
    __syncthreads();
    if (t < 64) part[(size_t)blockIdx.x * 64 + t] = gl[t];   // plain store
}

// ---- reduce partials (nPart x 64) + fold N*b2 + FC, single block ----

__global__ __launch_bounds__(1024) void reduce_fc_k(
        const float* __restrict__ part, const float* __restrict__ b2,
        const float* __restrict__ w, const float* __restrict__ b,
        float* __restrict__ out, int n, int nPart) {
    __shared__ float ls[1024];
    const int t = threadIdx.x;
    const int c = t & 63, pg = t >> 6;          // 16 p-groups x 64 channels
    float acc = 0.f;
    for (int p = pg; p < nPart; p += 16) acc += part[(size_t)p * 64 + c];
    ls[t] = acc;
    __syncthreads();
    if (t < 64) {
        float s = 0.f;
#pragma unroll
        for (int i = 0; i < 16; i++) s += ls[i * 64 + t];
        ls[t] = s + (float)n * b2[t];                        // fold layer-2 bias
    }
    __syncthreads();
    if (t < 2) {
        float a = b[t];
        for (int cc = 0; cc < 64; cc++) a = fmaf(ls[cc], w[cc * 2 + t], a);
        out[t] = a;
    }
}

// ---------------- launch ----------------

static inline size_t align256(size_t x) { return (x + 255) & ~(size_t)255; }

extern "C" void kernel_launch(void* const* d_in, const int* in_sizes, int n_in,
                              void* d_out, int out_size, void* d_ws, size_t ws_size,
                              hipStream_t stream) {
    const float* x     = (const float*)d_in[0];
    const int*   ei    = (const int*)  d_in[1];
    const float* W1    = (const float*)d_in[2];
    const float* asrc1 = (const float*)d_in[3];
    const float* adst1 = (const float*)d_in[4];
    const float* b1    = (const float*)d_in[5];
    const float* W2    = (const float*)d_in[6];
    const float* asrc2 = (const float*)d_in[7];
    const float* adst2 = (const float*)d_in[8];
    const float* b2    = (const float*)d_in[9];
    const float* fcw   = (const float*)d_in[10];
    const float* fcb   = (const float*)d_in[11];
    float* out = (float*)d_out;

    const int N = in_sizes[0] / 128;
    const int E = in_sizes[1] / 2;
    const int ITEMS = E + N;
    const int NB = (N + 255) >> 8;
    const int NPOOL = 2048;

    // workspace carve-up
    char* w = (char*)d_ws;
    size_t off = 0;
    int* offs  = (int*)(w + off); off = align256(off + (size_t)(N + 1) * 4);
    int* bOff  = (int*)(w + off); off = align256(off + 512 * 4);
    int* bFill = (int*)(w + off); off = align256(off + 512 * 4);
    int* csr   = (int*)(w + off); off = align256(off + (size_t)ITEMS * 4);
    int2* binned = (int2*)(w + off); off = align256(off + ((size_t)NB << 13) * 8);
    float* As = (float*)(w + off); off = align256(off + (size_t)N * 4 * 4);
    float* Ad = (float*)(w + off); off = align256(off + (size_t)N * 4 * 4);
    float* part = (float*)(w + off); off = align256(off + (size_t)NPOOL * 64 * 4);
    unsigned short* bufH = (unsigned short*)(w + off); off = align256(off + (size_t)N * 128 * 2);
    unsigned short* bufO = (unsigned short*)(w + off); off = align256(off + (size_t)N * 128 * 2);

    // --- build CSR (by dst, self loops included) ---
    hipMemsetAsync(bFill, 0, 512 * sizeof(int), stream);
    bin_scatter_k<<<(ITEMS + 4095) / 4096, 256, 0, stream>>>(ei, bFill, binned, E, N);
    bucket_scan_k<<<1, 512, 0, stream>>>(bFill, bOff, NB);
    csr_build_k<<<NB, 256, 0, stream>>>(binned, bOff, bFill, offs, csr, N, ITEMS);

    // --- layer 1 ---
    gemm_alpha_mfma<128, false><<<(N + 63) / 64, 256, 0, stream>>>(
        x, W1, asrc1, adst1, bufH, As, Ad, N);
    agg128_k<true><<<(N * 64 + 255) / 256, 256, 0, stream>>>(
        bufH, As, Ad, offs, csr, b1, bufO, N);

    // --- layer 2 ---
    gemm_alpha_mfma<64, true><<<(N + 63) / 64, 256, 0, stream>>>(
        bufO, W2, asrc2, adst2, bufH, As, Ad, N);
    agg64_pool_k<<<NPOOL, 256, 0, stream>>>(
        bufH, As, Ad, offs, csr, part, N);

    // --- reduce partials + fc ---
    reduce_fc_k<<<1, 1024, 0, stream>>>(part, b2, fcw, fcb, out, N, NPOOL);
}

// Round 16
// 245.667 us; speedup vs baseline: 1.1237x; 1.0109x over previous
//
#include <hip/hip_runtime.h>
#include <hip/hip_bf16.h>
#include <math.h>

// ---------------- fp16 helpers ----------------

using pkh2 = decltype(__builtin_amdgcn_cvt_pkrtz(0.f, 0.f));   // 2 x __fp16
typedef __fp16 half8v __attribute__((ext_vector_type(8)));     // MFMA A/B frag
typedef __attribute__((ext_vector_type(4))) float f32x4;       // MFMA accumulator

__device__ __forceinline__ unsigned cvt2h(float a, float b) {  // 2xf32 -> packed f16
    pkh2 r = __builtin_amdgcn_cvt_pkrtz(a, b);
    return __builtin_bit_cast(unsigned, r);
}
__device__ __forceinline__ unsigned short f2h(float f) {
    return __builtin_bit_cast(unsigned short, (_Float16)f);
}

// acc += wpair . hpair  (both packed f16 pairs), f32 accumulate
__device__ __forceinline__ float fdot2b(unsigned wp, unsigned hp, float c) {
#if __has_builtin(__builtin_amdgcn_fdot2)
    return __builtin_amdgcn_fdot2(__builtin_bit_cast(pkh2, wp),
                                  __builtin_bit_cast(pkh2, hp), c, false);
#else
    pkh2 w = __builtin_bit_cast(pkh2, wp), h = __builtin_bit_cast(pkh2, hp);
    return fmaf((float)w[0], (float)h[0], fmaf((float)w[1], (float)h[1], c));
#endif
}

// ================= CSR build v4: fixed-capacity buckets, packed items =========
// Bucket b = dst>>8; within a bucket only dst&255 is needed, so an item packs
// to 32 bits: src | (dst&255)<<24  (REQUIRES src < 2^24; here N=100k).
// Random dst -> Poisson counts (mu~4350, sigma~66); CAP=8192 ~ 58 sigma.
// Chain: memsetAsync(fill) -> bin_scatter -> csr_build (per-bucket prefix of
// counts + hist + scan + scatter, all in one block; binned 2nd pass L2-hot).

#define BCAP_LOG 13                      // 8192 items per bucket

__global__ __launch_bounds__(256) void bin_scatter_k(const int* __restrict__ ei,
                                                     int* __restrict__ bucketFill,
                                                     unsigned* __restrict__ binned,
                                                     int E, int N) {
    __shared__ int cnt[512];
    __shared__ int base[512];
    const int ITEMS = E + N;
    const int t = threadIdx.x;
    const int chunk0 = blockIdx.x * 4096;
    for (int b = t; b < 512; b += 256) cnt[b] = 0;
    __syncthreads();
    int s[16], d[16], r[16];
#pragma unroll
    for (int j = 0; j < 16; j++) {
        int i = chunk0 + j * 256 + t;
        if (i < ITEMS) {
            if (i < E) { s[j] = ei[i]; d[j] = ei[E + i]; }
            else       { s[j] = d[j] = i - E; }
            r[j] = atomicAdd(&cnt[d[j] >> 8], 1);
        } else d[j] = -1;
    }
    __syncthreads();
    for (int b = t; b < 512; b += 256) {
        int c = cnt[b];
        base[b] = c ? atomicAdd(&bucketFill[b], c) : 0;   // global chunk reserve
    }
    __syncthreads();
#pragma unroll
    for (int j = 0; j < 16; j++)
        if (d[j] >= 0) {
            int b = d[j] >> 8;
            binned[((size_t)b << BCAP_LOG) + base[b] + r[j]] =
                (unsigned)s[j] | ((unsigned)(d[j] & 255) << 24);
        }
}

// fused per-bucket: bucket-offset prefix + node histogram + scan + scatter
__global__ void csr_build_k(const unsigned* __restrict__ binned,
                            const int* __restrict__ bucketCnt,
                            int* __restrict__ offs, int* __restrict__ csr,
                            int N, int ITEMS, int NB) {
    __shared__ int cnt[256];
    __shared__ int obase[256];
    __shared__ int fill[256];
    __shared__ int red[256];
    const int b = blockIdx.x, t = threadIdx.x;
    // --- prefix of bucket counts [0, b) -> beg ---
    int pre = 0;
    for (int i = t; i < b; i += 256) pre += bucketCnt[i];
    red[t] = pre;
    cnt[t] = 0; fill[t] = 0;
    __syncthreads();
    for (int offr = 128; offr >= 1; offr >>= 1) {
        if (t < offr) red[t] += red[t + offr];
        __syncthreads();
    }
    const int beg = red[0];
    const int c = bucketCnt[b];
    const unsigned* bp = &binned[(size_t)b << BCAP_LOG];
    for (int i = t; i < c; i += 256)
        atomicAdd(&cnt[bp[i] >> 24], 1);
    __syncthreads();
    int v = cnt[t];
    obase[t] = v;
    __syncthreads();
    for (int off = 1; off < 256; off <<= 1) {
        int a = (t >= off) ? obase[t - off] : 0;
        __syncthreads();
        obase[t] += a;
        __syncthreads();
    }
    obase[t] -= v;                        // bucket-local exclusive scan
    int node = b * 256 + t;
    if (node < N) offs[node] = beg + obase[t];
    if (node == N - 1) offs[N] = ITEMS;
    __syncthreads();
    for (int i = t; i < c; i += 256) {    // 2nd pass: L2-hot
        unsigned p = bp[i];
        int dlow = p >> 24;
        int r = atomicAdd(&fill[dlow], 1);
        csr[beg + obase[dlow] + r] = (int)(p & 0xFFFFFFu);
    }
}

// ======= MFMA GEMM: Y[M,NCOL](f16) = X[M,128] @ W[128,NCOL] + fused alpha =======
// v_mfma_f32_16x16x32_f16, fragment layouts (dtype-independent, m89/m121):
//   A: lane l holds A[l&15][(l>>4)*8 + j];  B: lane l holds B[(l>>4)*8 + j][l&15]
//   D: lane l, reg j -> row (l>>4)*4+j, col l&15

template<int NCOL, bool XF16>
__global__ __launch_bounds__(256) void gemm_alpha_mfma(
        const void* __restrict__ Xv, const float* __restrict__ W,
        const float* __restrict__ asrc, const float* __restrict__ adst,
        unsigned short* __restrict__ Y, float* __restrict__ As,
        float* __restrict__ Ad, int M) {
    constexpr int NT = NCOL / 16;            // 8 (layer1) or 4 (layer2)
    __shared__ alignas(16) short alds[4 * 4 * 64 * 8];      // [w][ks][lane][8]
    __shared__ alignas(16) short blds[NT * 4 * 64 * 8];     // [nt][ks][lane][8]

    const int t    = threadIdx.x;
    const int w    = t >> 6, lane = t & 63;
    const int row0 = blockIdx.x * 64;

    if constexpr (!XF16) {
        const float* X = (const float*)Xv;
#pragma unroll
        for (int i = 0; i < 8; i++) {
            int flat = (i * 256 + t) * 4;
            int r = flat >> 7, k0 = flat & 127;
            int gr = row0 + r;
            float4 v = make_float4(0.f, 0.f, 0.f, 0.f);
            if (gr < M) v = *(const float4*)&X[(size_t)gr * 128 + k0];
            uint2 u = make_uint2(cvt2h(v.x, v.y), cvt2h(v.z, v.w));
            int frag = ((r >> 4) * 4 + (k0 >> 5)) * 64 + ((((k0 & 31) >> 3) << 4) | (r & 15));
            *(uint2*)&alds[frag * 8 + (k0 & 7)] = u;
        }
    } else {
        const unsigned short* X = (const unsigned short*)Xv;
#pragma unroll
        for (int i = 0; i < 4; i++) {
            int flat = (i * 256 + t) * 8;
            int r = flat >> 7, k0 = flat & 127;
            int gr = row0 + r;
            uint4 v = make_uint4(0u, 0u, 0u, 0u);
            if (gr < M) v = *(const uint4*)&X[(size_t)gr * 128 + k0];
            int frag = ((r >> 4) * 4 + (k0 >> 5)) * 64 + ((((k0 & 31) >> 3) << 4) | (r & 15));
            *(uint4*)&alds[frag * 8] = v;   // k0 % 8 == 0
        }
    }

    {
        constexpr int KQ = 256 / NCOL;
        constexpr int BITER = 32 / KQ;
        int c = t % NCOL, kq = t / NCOL;
        int nt = c >> 4, n = c & 15;
#pragma unroll
        for (int i = 0; i < BITER; i++) {
            int k0 = (i * KQ + kq) * 4;
            uint2 u = make_uint2(
                cvt2h(W[(size_t)(k0 + 0) * NCOL + c], W[(size_t)(k0 + 1) * NCOL + c]),
                cvt2h(W[(size_t)(k0 + 2) * NCOL + c], W[(size_t)(k0 + 3) * NCOL + c]));
            int frag = (nt * 4 + (k0 >> 5)) * 64 + ((((k0 & 31) >> 3) << 4) | n);
            *(uint2*)&blds[frag * 8 + (k0 & 7)] = u;
        }
    }
    __syncthreads();

    f32x4 acc[NT];
#pragma unroll
    for (int nt = 0; nt < NT; nt++) acc[nt] = (f32x4){0.f, 0.f, 0.f, 0.f};
#pragma unroll
    for (int ks = 0; ks < 4; ks++) {
        half8v a = *(half8v*)&alds[((w * 4 + ks) * 64 + lane) * 8];
#pragma unroll
        for (int nt = 0; nt < NT; nt++) {
            half8v b = *(half8v*)&blds[((nt * 4 + ks) * 64 + lane) * 8];
            acc[nt] = __builtin_amdgcn_mfma_f32_16x16x32_f16(a, b, acc[nt], 0, 0, 0);
        }
    }

    const int g = lane >> 4, col = lane & 15;
    float ps[4][4] = {}, pd[4][4] = {};
#pragma unroll
    for (int nt = 0; nt < NT; nt++) {
        float av = asrc[nt * 16 + col];
        float dv = adst[nt * 16 + col];
        int h = (NCOL == 128) ? (nt >> 1) : nt;
#pragma unroll
        for (int j = 0; j < 4; j++) {
            float v = acc[nt][j];
            ps[j][h] = fmaf(v, av, ps[j][h]);
            pd[j][h] = fmaf(v, dv, pd[j][h]);
            int gr = row0 + w * 16 + 4 * g + j;
            if (gr < M) Y[(size_t)gr * NCOL + nt * 16 + col] = f2h(v);
        }
    }
#pragma unroll
    for (int m = 1; m < 16; m <<= 1) {
#pragma unroll
        for (int j = 0; j < 4; j++)
#pragma unroll
            for (int h = 0; h < 4; h++) {
                ps[j][h] += __shfl_xor(ps[j][h], m);
                pd[j][h] += __shfl_xor(pd[j][h], m);
            }
    }
    if (col == 0) {
#pragma unroll
        for (int j = 0; j < 4; j++) {
            int gr = row0 + w * 16 + 4 * g + j;
            if (gr < M) {
#pragma unroll
                for (int h = 0; h < 4; h++) {
                    As[gr * 4 + h] = ps[j][h];
                    Ad[gr * 4 + h] = pd[j][h];
                }
            }
        }
    }
}

// ------- aggregation: one wave per dst node ----------------------------------
// out[i] = ( sum_{e:dst=i} exp(leaky(As[src]+Ad[i])) * h[src] ) / sum exp(...)
// (segment-max dropped: softmax ratio invariant; weights < e^~5 -> f16-safe)
// Four edges per lane in flight + f16 perm/fdot2 accumulate. Register-only.
// R7/R11/R14/R15 all land at 72us: mixed random-gather/VALU floor.

template<bool RELU>
__global__ void agg128_k(const unsigned short* __restrict__ Hb,
                         const float* __restrict__ As, const float* __restrict__ Ad,
                         const int* __restrict__ offs, const int* __restrict__ csr,
                         const float* __restrict__ bias,
                         unsigned short* __restrict__ Outb, int n) {
    int wid  = (blockIdx.x * blockDim.x + threadIdx.x) >> 6;
    int lane = threadIdx.x & 63;
    if (wid >= n) return;
    const int g = lane >> 4;          // edge-slot group (0..3)
    const int q = lane & 15;          // channel octet
    const int head = q >> 2;
    const int beg = offs[wid], end = offs[wid + 1];
    const float ad = Ad[wid * 4 + head];
    float acc[8];
#pragma unroll
    for (int k = 0; k < 8; k++) acc[k] = 0.f;
    float sw = 0.f;

    for (int cb = beg; cb < end; cb += 64) {
        const int nc = min(64, end - cb);
        const int sreg = csr[cb + (lane < nc ? lane : 0)];   // 1 coalesced load
        const int ncr = (nc + 15) & ~15;
        for (int j = 0; j < ncr; j += 16) {
            const int e0 = j + g, e1 = e0 + 4, e2 = e0 + 8, e3 = e0 + 12;
            const bool v0 = e0 < nc, v1 = e1 < nc, v2 = e2 < nc, v3 = e3 < nc;
            const int s0 = __shfl(sreg, v0 ? e0 : 0);
            const int s1 = __shfl(sreg, v1 ? e1 : 0);
            const int s2 = __shfl(sreg, v2 ? e2 : 0);
            const int s3 = __shfl(sreg, v3 ? e3 : 0);
            const uint4 hA = *(const uint4*)&Hb[(size_t)s0 * 128 + q * 8];
            const uint4 hB = *(const uint4*)&Hb[(size_t)s1 * 128 + q * 8];
            const uint4 hC = *(const uint4*)&Hb[(size_t)s2 * 128 + q * 8];
            const uint4 hD = *(const uint4*)&Hb[(size_t)s3 * 128 + q * 8];
            float ev0 = As[s0 * 4 + head] + ad; ev0 = ev0 > 0.f ? ev0 : 0.2f * ev0;
            float ev1 = As[s1 * 4 + head] + ad; ev1 = ev1 > 0.f ? ev1 : 0.2f * ev1;
            float ev2 = As[s2 * 4 + head] + ad; ev2 = ev2 > 0.f ? ev2 : 0.2f * ev2;
            float ev3 = As[s3 * 4 + head] + ad; ev3 = ev3 > 0.f ? ev3 : 0.2f * ev3;
            const float w0 = v0 ? __expf(ev0) : 0.f;
            const float w1 = v1 ? __expf(ev1) : 0.f;
            const float w2 = v2 ? __expf(ev2) : 0.f;
            const float w3 = v3 ? __expf(ev3) : 0.f;
            sw += (w0 + w1) + (w2 + w3);
            const unsigned wp01 = cvt2h(w0, w1);
            const unsigned wp23 = cvt2h(w2, w3);
#pragma unroll
            for (int k = 0; k < 4; k++) {
                unsigned a0 = (&hA.x)[k], a1 = (&hB.x)[k];
                unsigned a2 = (&hC.x)[k], a3 = (&hD.x)[k];
                acc[2 * k]     = fdot2b(wp01, __builtin_amdgcn_perm(a1, a0, 0x05040100u), acc[2 * k]);
                acc[2 * k]     = fdot2b(wp23, __builtin_amdgcn_perm(a3, a2, 0x05040100u), acc[2 * k]);
                acc[2 * k + 1] = fdot2b(wp01, __builtin_amdgcn_perm(a1, a0, 0x07060302u), acc[2 * k + 1]);
                acc[2 * k + 1] = fdot2b(wp23, __builtin_amdgcn_perm(a3, a2, 0x07060302u), acc[2 * k + 1]);
            }
        }
    }

    sw += __shfl_xor(sw, 16); sw += __shfl_xor(sw, 32);
#pragma unroll
    for (int k = 0; k < 8; k++) {
        acc[k] += __shfl_xor(acc[k], 16);
        acc[k] += __shfl_xor(acc[k], 32);
    }
    if (g == 0) {
        const float inv = 1.f / sw;
        float o[8];
#pragma unroll
        for (int k = 0; k < 8; k++) {
            float v = fmaf(acc[k], inv, bias[q * 8 + k]);
            if (RELU) v = fmaxf(v, 0.f);
            o[k] = v;
        }
        uint4 ov = make_uint4(cvt2h(o[0], o[1]), cvt2h(o[2], o[3]),
                              cvt2h(o[4], o[5]), cvt2h(o[6], o[7]));
        *(uint4*)&Outb[(size_t)wid * 128 + q * 8] = ov;
    }
}

// Layer-2 aggregate FUSED with global add pool, grid-strided over nodes.
// Per-wave register accumulation; per-block partial stores (NO global atomics).

__global__ __launch_bounds__(256) void agg64_pool_k(
        const unsigned short* __restrict__ Hb,
        const float* __restrict__ As, const float* __restrict__ Ad,
        const int* __restrict__ offs, const int* __restrict__ csr,
        float* __restrict__ part, int n) {
    __shared__ float gl[64];
    const int t = threadIdx.x;
    if (t < 64) gl[t] = 0.f;
    __syncthreads();
    const int wave0  = (blockIdx.x * blockDim.x + t) >> 6;
    const int nWaves = (gridDim.x * blockDim.x) >> 6;
    const int lane = t & 63;
    const int g = lane >> 3;          // edge-slot group (0..7)
    const int q = lane & 7;           // channel octet
    const int head = q >> 1;
    float gsum[8];
#pragma unroll
    for (int k = 0; k < 8; k++) gsum[k] = 0.f;

    for (int wid = wave0; wid < n; wid += nWaves) {
        const int beg = offs[wid], end = offs[wid + 1];
        const float ad = Ad[wid * 4 + head];
        float acc[8];
#pragma unroll
        for (int k = 0; k < 8; k++) acc[k] = 0.f;
        float sw = 0.f;
        for (int cb = beg; cb < end; cb += 64) {
            const int nc = min(64, end - cb);
            const int sreg = csr[cb + (lane < nc ? lane : 0)];
            const int ncr = (nc + 31) & ~31;
            for (int j = 0; j < ncr; j += 32) {
                const int e0 = j + g, e1 = e0 + 8, e2 = e0 + 16, e3 = e0 + 24;
                const bool v0 = e0 < nc, v1 = e1 < nc, v2 = e2 < nc, v3 = e3 < nc;
                const int s0 = __shfl(sreg, v0 ? e0 : 0);
                const int s1 = __shfl(sreg, v1 ? e1 : 0);
                const int s2 = __shfl(sreg, v2 ? e2 : 0);
                const int s3 = __shfl(sreg, v3 ? e3 : 0);
                const uint4 hA = *(const uint4*)&Hb[(size_t)s0 * 64 + q * 8];
                const uint4 hB = *(const uint4*)&Hb[(size_t)s1 * 64 + q * 8];
                const uint4 hC = *(const uint4*)&Hb[(size_t)s2 * 64 + q * 8];
                const uint4 hD = *(const uint4*)&Hb[(size_t)s3 * 64 + q * 8];
                float ev0 = As[s0 * 4 + head] + ad; ev0 = ev0 > 0.f ? ev0 : 0.2f * ev0;
                float ev1 = As[s1 * 4 + head] + ad; ev1 = ev1 > 0.f ? ev1 : 0.2f * ev1;
                float ev2 = As[s2 * 4 + head] + ad; ev2 = ev2 > 0.f ? ev2 : 0.2f * ev2;
                float ev3 = As[s3 * 4 + head] + ad; ev3 = ev3 > 0.f ? ev3 : 0.2f * ev3;
                const float w0 = v0 ? __expf(ev0) : 0.f;
                const float w1 = v1 ? __expf(ev1) : 0.f;
                const float w2 = v2 ? __expf(ev2) : 0.f;
                const float w3 = v3 ? __expf(ev3) : 0.f;
                sw += (w0 + w1) + (w2 + w3);
                const unsigned wp01 = cvt2h(w0, w1);
                const unsigned wp23 = cvt2h(w2, w3);
#pragma unroll
                for (int k = 0; k < 4; k++) {
                    unsigned a0 = (&hA.x)[k], a1 = (&hB.x)[k];
                    unsigned a2 = (&hC.x)[k], a3 = (&hD.x)[k];
                    acc[2 * k]     = fdot2b(wp01, __builtin_amdgcn_perm(a1, a0, 0x05040100u), acc[2 * k]);
                    acc[2 * k]     = fdot2b(wp23, __builtin_amdgcn_perm(a3, a2, 0x05040100u), acc[2 * k]);
                    acc[2 * k + 1] = fdot2b(wp01, __builtin_amdgcn_perm(a1, a0, 0x07060302u), acc[2 * k + 1]);
                    acc[2 * k + 1] = fdot2b(wp23, __builtin_amdgcn_perm(a3, a2, 0x07060302u), acc[2 * k + 1]);
                }
            }
        }
        sw += __shfl_xor(sw, 8); sw += __shfl_xor(sw, 16); sw += __shfl_xor(sw, 32);
#pragma unroll
        for (int k = 0; k < 8; k++) {
            acc[k] += __shfl_xor(acc[k], 8);
            acc[k] += __shfl_xor(acc[k], 16);
            acc[k] += __shfl_xor(acc[k], 32);
        }
        if (g == 0) {
            const float inv = 1.f / sw;
#pragma unroll
            for (int k = 0; k < 8; k++) gsum[k] = fmaf(acc[k], inv, gsum[k]);
        }
    }

    if (g == 0) {
#pragma unroll
        for (int k = 0; k < 8; k++) atomicAdd(&gl[q * 8 + k], gsum[k]);  // LDS only
    }
    __syncthreads();
    if (t < 64) part[(size_t)blockIdx.x * 64 + t] = gl[t];   // plain store
}

// ---- reduce partials (nPart x 64) + fold N*b2 + FC, single block ----

__global__ __launch_bounds__(1024) void reduce_fc_k(
        const float* __restrict__ part, const float* __restrict__ b2,
        const float* __restrict__ w, const float* __restrict__ b,
        float* __restrict__ out, int n, int nPart) {
    __shared__ float ls[1024];
    const int t = threadIdx.x;
    const int c = t & 63, pg = t >> 6;          // 16 p-groups x 64 channels
    float acc = 0.f;
    for (int p = pg; p < nPart; p += 16) acc += part[(size_t)p * 64 + c];
    ls[t] = acc;
    __syncthreads();
    if (t < 64) {
        float s = 0.f;
#pragma unroll
        for (int i = 0; i < 16; i++) s += ls[i * 64 + t];
        ls[t] = s + (float)n * b2[t];                        // fold layer-2 bias
    }
    __syncthreads();
    if (t < 2) {
        float a = b[t];
        for (int cc = 0; cc < 64; cc++) a = fmaf(ls[cc], w[cc * 2 + t], a);
        out[t] = a;
    }
}

// ---------------- launch ----------------

static inline size_t align256(size_t x) { return (x + 255) & ~(size_t)255; }

extern "C" void kernel_launch(void* const* d_in, const int* in_sizes, int n_in,
                              void* d_out, int out_size, void* d_ws, size_t ws_size,
                              hipStream_t stream) {
    const float* x     = (const float*)d_in[0];
    const int*   ei    = (const int*)  d_in[1];
    const float* W1    = (const float*)d_in[2];
    const float* asrc1 = (const float*)d_in[3];
    const float* adst1 = (const float*)d_in[4];
    const float* b1    = (const float*)d_in[5];
    const float* W2    = (const float*)d_in[6];
    const float* asrc2 = (const float*)d_in[7];
    const float* adst2 = (const float*)d_in[8];
    const float* b2    = (const float*)d_in[9];
    const float* fcw   = (const float*)d_in[10];
    const float* fcb   = (const float*)d_in[11];
    float* out = (float*)d_out;

    const int N = in_sizes[0] / 128;
    const int E = in_sizes[1] / 2;
    const int ITEMS = E + N;
    const int NB = (N + 255) >> 8;
    const int NPOOL = 2048;

    // workspace carve-up
    char* w = (char*)d_ws;
    size_t off = 0;
    int* offs  = (int*)(w + off); off = align256(off + (size_t)(N + 1) * 4);
    int* bFill = (int*)(w + off); off = align256(off + 512 * 4);
    int* csr   = (int*)(w + off); off = align256(off + (size_t)ITEMS * 4);
    unsigned* binned = (unsigned*)(w + off); off = align256(off + ((size_t)NB << 13) * 4);
    float* As = (float*)(w + off); off = align256(off + (size_t)N * 4 * 4);
    float* Ad = (float*)(w + off); off = align256(off + (size_t)N * 4 * 4);
    float* part = (float*)(w + off); off = align256(off + (size_t)NPOOL * 64 * 4);
    unsigned short* bufH = (unsigned short*)(w + off); off = align256(off + (size_t)N * 128 * 2);
    unsigned short* bufO = (unsigned short*)(w + off); off = align256(off + (size_t)N * 128 * 2);

    // --- build CSR (by dst, self loops included) ---
    hipMemsetAsync(bFill, 0, 512 * sizeof(int), stream);
    bin_scatter_k<<<(ITEMS + 4095) / 4096, 256, 0, stream>>>(ei, bFill, binned, E, N);
    csr_build_k<<<NB, 256, 0, stream>>>(binned, bFill, offs, csr, N, ITEMS, NB);

    // --- layer 1 ---
    gemm_alpha_mfma<128, false><<<(N + 63) / 64, 256, 0, stream>>>(
        x, W1, asrc1, adst1, bufH, As, Ad, N);
    agg128_k<true><<<(N * 64 + 255) / 256, 256, 0, stream>>>(
        bufH, As, Ad, offs, csr, b1, bufO, N);

    // --- layer 2 ---
    gemm_alpha_mfma<64, true><<<(N + 63) / 64, 256, 0, stream>>>(
        bufO, W2, asrc2, adst2, bufH, As, Ad, N);
    agg64_pool_k<<<NPOOL, 256, 0, stream>>>(
        bufH, As, Ad, offs, csr, part, N);

    // --- reduce partials + fc ---
    reduce_fc_k<<<1, 1024, 0, stream>>>(part, b2, fcw, fcb, out, N, NPOOL);
}